// Round 8
// baseline (680.553 us; speedup 1.0000x reference)
//
#include <hip/hip_runtime.h>
#include <hip/hip_bf16.h>
#include <math.h>

#define T_TOK 2048
#define HID   2048
#define NE    32
#define DF    1024
#define DSZ   4096
#define TOPK  6
#define NGRP  8
#define TOPKG 4
#define RSCALE 2.5f
#define EXT_E 36            // 32 routed + 4 shared pseudo-experts
#define NSLOT 20480         // 12288 routed + 8192 shared slots

typedef __attribute__((ext_vector_type(8))) short short8;
typedef __attribute__((ext_vector_type(4))) short short4v;
typedef __attribute__((ext_vector_type(4))) float f32x4;

typedef __attribute__((address_space(1))) const void gv1;
typedef __attribute__((address_space(3))) void lv3;

static __device__ __forceinline__ void gload16(const void* g, void* l) {
    __builtin_amdgcn_global_load_lds((gv1*)g, (lv3*)l, 16, 0, 0);
}

static __device__ __forceinline__ unsigned short f2b(float f) {
    union { float f; unsigned u; } v; v.f = f;
    unsigned r = v.u + 0x7fffu + ((v.u >> 16) & 1u);
    return (unsigned short)(r >> 16);
}

static __device__ __forceinline__ unsigned short b16(float f) {
    union { __hip_bfloat16 h; unsigned short u; } c;
    c.h = __float2bfloat16(f);
    return c.u;
}

static __device__ __forceinline__ float b2f(unsigned short b) {
    union { float f; unsigned u; } v; v.u = ((unsigned)b) << 16;
    return v.f;
}

// ---------------- router (one block per token), fused x->bf16 ----------------
__global__ __launch_bounds__(256)
void router_kernel(const float* __restrict__ x, const float* __restrict__ rw,
                   const float* __restrict__ rb,
                   int* __restrict__ tidx, float* __restrict__ tw,
                   int* __restrict__ counts, unsigned short* __restrict__ xb) {
    __shared__ float xs[HID];
    __shared__ float part[256];
    __shared__ float scores[NE];
    __shared__ float sfc[NE];
    int t = blockIdx.x;
    int tid = threadIdx.x;
    for (int i = tid; i < HID / 4; i += 256) {
        ((float4*)xs)[i] = ((const float4*)(x + (size_t)t * HID))[i];
    }
    __syncthreads();
    {
        float4 a = ((const float4*)xs)[tid * 2];
        float4 b = ((const float4*)xs)[tid * 2 + 1];
        short8 o;
        o[0] = (short)f2b(a.x); o[1] = (short)f2b(a.y); o[2] = (short)f2b(a.z); o[3] = (short)f2b(a.w);
        o[4] = (short)f2b(b.x); o[5] = (short)f2b(b.y); o[6] = (short)f2b(b.z); o[7] = (short)f2b(b.w);
        *(short8*)(xb + (size_t)t * HID + tid * 8) = o;
    }
    int e = tid & 31, ch = tid >> 5;
    const float* w = rw + (size_t)e * HID + ch * 256;
    const float* xv = xs + ch * 256;
    float p = 0.f;
    #pragma unroll 8
    for (int k = 0; k < 256; ++k) p += xv[k] * w[k];
    part[tid] = p;
    __syncthreads();
    if (tid < 32) {
        float l = 0.f;
        #pragma unroll
        for (int c = 0; c < 8; ++c) l += part[c * 32 + tid];
        float s = 1.f / (1.f + expf(-l));
        scores[tid] = s;
        sfc[tid] = s + rb[tid];
    }
    __syncthreads();
    if (tid == 0) {
        float gs[NGRP];
        for (int g = 0; g < NGRP; ++g) {
            float v[4];
            for (int i = 0; i < 4; ++i) v[i] = sfc[g * 4 + i];
            int bi = 0;
            for (int i = 1; i < 4; ++i) if (v[i] > v[bi]) bi = i;
            float m1 = v[bi]; v[bi] = -INFINITY;
            int bj = 0;
            for (int i = 1; i < 4; ++i) if (v[i] > v[bj]) bj = i;
            gs[g] = m1 + v[bj];
        }
        bool gsel[NGRP];
        for (int g = 0; g < NGRP; ++g) gsel[g] = false;
        for (int k = 0; k < TOPKG; ++k) {
            int bi = -1; float b = -INFINITY;
            for (int g = 0; g < NGRP; ++g)
                if (!gsel[g] && gs[g] > b) { b = gs[g]; bi = g; }
            gsel[bi] = true;
        }
        float masked[NE];
        for (int i = 0; i < NE; ++i) masked[i] = gsel[i >> 2] ? sfc[i] : 0.0f;
        int sel[TOPK]; float wv[TOPK]; float wsum = 0.f;
        for (int k = 0; k < TOPK; ++k) {
            int bi = -1; float b = -INFINITY;
            for (int i = 0; i < NE; ++i)
                if (masked[i] > b) { b = masked[i]; bi = i; }
            masked[bi] = -INFINITY;
            sel[k] = bi; wv[k] = scores[bi]; wsum += wv[k];
        }
        float inv = RSCALE / (wsum + 1e-20f);
        for (int k = 0; k < TOPK; ++k) {
            tidx[t * TOPK + k] = sel[k];
            tw[t * TOPK + k] = wv[k] * inv;
            atomicAdd(&counts[sel[k]], 1);
        }
    }
}

__global__ void scan_kernel(const int* __restrict__ counts, int* __restrict__ offsets) {
    if (threadIdx.x == 0) {
        int a = 0;
        for (int e2 = 0; e2 < NE; ++e2) { offsets[e2] = a; a += counts[e2]; }
        offsets[NE] = a;                          // = 12288
        for (int j = 1; j <= 4; ++j) offsets[NE + j] = 12288 + j * T_TOK;
    }
}

__global__ void scatter_kernel(const int* __restrict__ tidx, const float* __restrict__ tw,
                               const int* __restrict__ offsets, int* __restrict__ cursors,
                               int* __restrict__ perm, float* __restrict__ pw,
                               int* __restrict__ slot_of) {
    int t = blockIdx.x * blockDim.x + threadIdx.x;
    if (t >= T_TOK) return;
    for (int k = 0; k < TOPK; ++k) {
        int e = tidx[t * TOPK + k];
        int pos = atomicAdd(&cursors[e], 1);
        int slot = offsets[e] + pos;
        perm[slot] = t;
        pw[slot] = tw[t * TOPK + k];
        slot_of[t * TOPK + k] = slot;
    }
    #pragma unroll
    for (int j = 0; j < 4; ++j) {                 // shared pseudo-expert slots
        int slot = 12288 + j * T_TOK + t;
        perm[slot] = t;
        pw[slot] = 1.0f;
    }
}

// ============================================================================
// GEMM core with fp32-B inline staging + ds_read_b64_tr_b16 B-fragments.
// A: bf16 [rows][K], staged via global_load_lds with XOR-swizzled source.
// B: fp32 [K,N] (ldb runtime), staged: coalesced float4 reads -> RNE cvt ->
//    8B writes into subtiled LDS [k>>2][n>>4][k&3][n&15] (4k x 16n blocks).
// B-frag: 2x ds_read_b64_tr_b16 (offset 0 / 1024) -> 8 consecutive k per lane.
// ============================================================================
template<int MODE>   // 0 = up (C=act bf16 relu2*pw, A gathered via perm), 1 = down (C=slotout bf16)
__global__ __launch_bounds__(256, 2)
void gemm_tr_kernel(const unsigned short* __restrict__ Abuf,
                    const float* __restrict__ Wmain, const float* __restrict__ Wsh,
                    unsigned short* __restrict__ Cbuf, const int* __restrict__ offsets,
                    const int* __restrict__ perm, const float* __restrict__ pw) {
    constexpr int K = (MODE == 0) ? HID : DF;
    constexpr int N = (MODE == 0) ? DF : HID;
    __shared__ __align__(16) char lds[32768];
    char* As = lds;
    char* Bs = lds + 16384;

    int tid = threadIdx.x;
    int lane = tid & 63, wvid = tid >> 6, wr = wvid >> 1, wc = wvid & 1;

    int bz = blockIdx.z;
    int off = offsets[bz], end = offsets[bz + 1];
    int row0 = off + blockIdx.y * 128;
    if (row0 >= end) return;
    int n0 = blockIdx.x * 128;

    // B source (fp32, [K,N] natural layout)
    const float* Bsrc; long ldb;
    if (MODE == 0) {
        if (bz < NE) { Bsrc = Wmain + (size_t)bz * HID * DF; ldb = DF; }
        else         { Bsrc = Wsh + (size_t)(bz - NE) * DF;  ldb = DSZ; }
    } else {
        Bsrc = (bz < NE) ? (Wmain + (size_t)bz * DF * HID)
                         : (Wsh + (size_t)(bz - NE) * DF * HID);
        ldb = HID;
    }

    // ---- A staging role (global_load_lds, pre-swizzled source chunk) ----
    int lr = lane >> 3;
    int csrc = (((lane & 7) ^ lr) << 4);
    size_t abyte[4];
    int ldsoff[4];
    #pragma unroll
    for (int p = 0; p < 4; ++p) {
        int r = p * 32 + wvid * 8 + lr;
        int gr = row0 + r;
        if (gr > end - 1) gr = end - 1;
        int s = (MODE == 0) ? perm[gr] : gr;
        abyte[p] = (size_t)s * (K * 2);
        ldsoff[p] = (p * 32 + wvid * 8) * 128;
    }

    // ---- B staging role: 8 passes, (kr&3, nc&15) spread for bank uniformity ----
    int kr0 = (tid & 3) + ((tid >> 6) & 1) * 4;           // 0..7
    int nc  = ((tid >> 2) & 15) * 4 + (tid >> 7) * 64;    // 0..124
    int bwbase = (kr0 >> 2) * 1024 + (nc >> 4) * 128 + (kr0 & 3) * 32 + (nc & 15) * 2;

    // ---- B-frag tr_read lane base ----
    unsigned bsb = (unsigned)(uintptr_t)(lv3*)Bs + (unsigned)((lane >> 4) * 2048 + (lane & 15) * 8);

    f32x4 acc[4][4] = {};
    for (int k0 = 0; k0 < K; k0 += 64) {
        __syncthreads();
        // A: 4x global_load_lds dwordx4 (linear LDS dest == XOR-swizzled layout)
        #pragma unroll
        for (int p = 0; p < 4; ++p)
            gload16((const char*)Abuf + abyte[p] + k0 * 2 + csrc, As + ldsoff[p]);
        // B: fp32 coalesced read -> bf16 -> subtiled LDS
        {
            const float* bp = Bsrc + (size_t)(k0 + kr0) * ldb + n0 + nc;
            #pragma unroll
            for (int p = 0; p < 8; ++p) {
                float4 v = *(const float4*)(bp + (size_t)p * 8 * ldb);
                unsigned short h[4] = { b16(v.x), b16(v.y), b16(v.z), b16(v.w) };
                *(short4v*)(Bs + bwbase + p * 2048) = *(short4v*)h;
            }
        }
        __syncthreads();
        // compute: 2 k-steps of 32
        #pragma unroll
        for (int ks = 0; ks < 2; ++ks) {
            int r16 = lane & 15, kg = lane >> 4;
            short8 af[4];
            #pragma unroll
            for (int m = 0; m < 4; ++m) {
                int r = wr * 64 + m * 16 + r16;
                af[m] = *(const short8*)(As + r * 128 + ((ks * 64 + kg * 16) ^ ((r & 7) << 4)));
            }
            short4v t0[4], t1[4];
            #pragma unroll
            for (int n = 0; n < 4; ++n) {
                unsigned a = bsb + ks * 8192 + (wc * 4 + n) * 128;
                asm volatile("ds_read_b64_tr_b16 %0, %2\n\t"
                             "ds_read_b64_tr_b16 %1, %2 offset:1024"
                             : "=v"(t0[n]), "=v"(t1[n]) : "v"(a));
            }
            asm volatile("s_waitcnt lgkmcnt(0)" ::: "memory");
            __builtin_amdgcn_sched_barrier(0);
            #pragma unroll
            for (int n = 0; n < 4; ++n) {
                short8 bfr;
                bfr[0] = t0[n][0]; bfr[1] = t0[n][1]; bfr[2] = t0[n][2]; bfr[3] = t0[n][3];
                bfr[4] = t1[n][0]; bfr[5] = t1[n][1]; bfr[6] = t1[n][2]; bfr[7] = t1[n][3];
                #pragma unroll
                for (int m = 0; m < 4; ++m)
                    acc[m][n] = __builtin_amdgcn_mfma_f32_16x16x32_bf16(af[m], bfr, acc[m][n], 0, 0, 0);
            }
        }
    }

    // epilogue. D frag: col = lane&15, row = (lane>>4)*4 + j
    int r16 = lane & 15, rg = lane >> 4;
    #pragma unroll
    for (int m = 0; m < 4; ++m) {
        #pragma unroll
        for (int j = 0; j < 4; ++j) {
            int rr = row0 + wr * 64 + m * 16 + rg * 4 + j;
            if (rr < end) {
                if (MODE == 0) {
                    float scale = pw[rr];
                    #pragma unroll
                    for (int n = 0; n < 4; ++n) {
                        int cc = n0 + wc * 64 + n * 16 + r16;
                        float v = acc[m][n][j];
                        v = v > 0.f ? v * v : 0.f;
                        Cbuf[(size_t)rr * N + cc] = f2b(v * scale);
                    }
                } else {
                    #pragma unroll
                    for (int n = 0; n < 4; ++n) {
                        int cc = n0 + wc * 64 + n * 16 + r16;
                        Cbuf[(size_t)rr * N + cc] = f2b(acc[m][n][j]);
                    }
                }
            }
        }
    }
}

// ---------------- combine: out[t] = sum of 6 routed + 4 shared slot rows (bf16 in, f32 out) ----
__global__ void combine_kernel(const unsigned short* __restrict__ slotout,
                               const int* __restrict__ slot_of,
                               float* __restrict__ out) {
    int t = blockIdx.x, tid = threadIdx.x;
    int s[10];
    #pragma unroll
    for (int k = 0; k < TOPK; ++k) s[k] = slot_of[t * TOPK + k];
    #pragma unroll
    for (int j = 0; j < 4; ++j) s[TOPK + j] = 12288 + j * T_TOK + t;
    int c = tid * 8;
    float a[8] = {0.f, 0.f, 0.f, 0.f, 0.f, 0.f, 0.f, 0.f};
    #pragma unroll
    for (int k = 0; k < 10; ++k) {
        short8 v = *(const short8*)(slotout + (size_t)s[k] * HID + c);
        #pragma unroll
        for (int i = 0; i < 8; ++i) a[i] += b2f((unsigned short)v[i]);
    }
    *(float4*)(out + (size_t)t * HID + c) = make_float4(a[0], a[1], a[2], a[3]);
    *(float4*)(out + (size_t)t * HID + c + 4) = make_float4(a[4], a[5], a[6], a[7]);
}

extern "C" void kernel_launch(void* const* d_in, const int* in_sizes, int n_in,
                              void* d_out, int out_size, void* d_ws, size_t ws_size,
                              hipStream_t stream) {
    const float* x     = (const float*)d_in[0];
    const float* rw    = (const float*)d_in[1];
    const float* rb    = (const float*)d_in[2];
    const float* w_up  = (const float*)d_in[3];
    const float* w_dn  = (const float*)d_in[4];
    const float* sh_up = (const float*)d_in[5];
    const float* sh_dn = (const float*)d_in[6];
    float* out = (float*)d_out;
    char* ws = (char*)d_ws;

    int*   counts  = (int*)(ws);
    int*   cursors = (int*)(ws + 128);
    int*   offsets = (int*)(ws + 256);            // 37 ints
    int*   tidx    = (int*)(ws + 1024);           // 12288 int
    float* tw      = (float*)(ws + 50176);        // 12288 f32
    int*   slot_of = (int*)(ws + 99328);          // 12288 int
    int*   perm    = (int*)(ws + 148480);         // 20480 int
    float* pw      = (float*)(ws + 230400);       // 20480 f32
    unsigned short* xb   = (unsigned short*)(ws + 312320);     // [2048][2048] bf16 (8.4MB)
    unsigned short* act  = (unsigned short*)(ws + 8700928);    // [20480][1024] bf16 (41.9MB)
    unsigned short* slotout = (unsigned short*)(ws + 50643968); // [20480][2048] bf16 (84MB)

    hipMemsetAsync(ws, 0, 256, stream);  // counts + cursors

    router_kernel<<<T_TOK, 256, 0, stream>>>(x, rw, rb, tidx, tw, counts, xb);
    scan_kernel<<<1, 64, 0, stream>>>(counts, offsets);
    scatter_kernel<<<(T_TOK + 255) / 256, 256, 0, stream>>>(tidx, tw, offsets, cursors,
                                                            perm, pw, slot_of);

    // up: A=xb gathered, B=w_up/sh_up fp32 inline, C=act
    gemm_tr_kernel<0><<<dim3(DF / 128, T_TOK / 128, EXT_E), 256, 0, stream>>>(
        xb, w_up, sh_up, act, offsets, perm, pw);

    // down: A=act, B=w_dn/sh_dn fp32 inline, C=slotout
    gemm_tr_kernel<1><<<dim3(HID / 128, T_TOK / 128, EXT_E), 256, 0, stream>>>(
        act, w_dn, sh_dn, slotout, offsets, perm, pw);

    combine_kernel<<<T_TOK, 256, 0, stream>>>(slotout, slot_of, out);
}

// Round 9
// 596.693 us; speedup vs baseline: 1.1405x; 1.1405x over previous
//
#include <hip/hip_runtime.h>
#include <hip/hip_bf16.h>
#include <math.h>

#define T_TOK 2048
#define HID   2048
#define NE    32
#define DF    1024
#define DSZ   4096
#define TOPK  6
#define NGRP  8
#define TOPKG 4
#define RSCALE 2.5f
#define EXT_E 36            // 32 routed + 4 shared pseudo-experts
#define NSLOT 20480         // 12288 routed + 8192 shared slots

typedef __attribute__((ext_vector_type(8))) short short8;
typedef __attribute__((ext_vector_type(4))) short short4v;
typedef __attribute__((ext_vector_type(4))) float f32x4;

typedef __attribute__((address_space(1))) const void gv1;
typedef __attribute__((address_space(3))) void lv3;

static __device__ __forceinline__ void gload16(const void* g, void* l) {
    __builtin_amdgcn_global_load_lds((gv1*)g, (lv3*)l, 16, 0, 0);
}

static __device__ __forceinline__ unsigned short f2b(float f) {
    union { float f; unsigned u; } v; v.f = f;
    unsigned r = v.u + 0x7fffu + ((v.u >> 16) & 1u);
    return (unsigned short)(r >> 16);
}

static __device__ __forceinline__ float b2f(unsigned short b) {
    union { float f; unsigned u; } v; v.u = ((unsigned)b) << 16;
    return v.f;
}

// ---------------- router (one block per token), fused x->bf16 ----------------
__global__ __launch_bounds__(256)
void router_kernel(const float* __restrict__ x, const float* __restrict__ rw,
                   const float* __restrict__ rb,
                   int* __restrict__ tidx, float* __restrict__ tw,
                   int* __restrict__ counts, unsigned short* __restrict__ xb) {
    __shared__ float xs[HID];
    __shared__ float part[256];
    __shared__ float scores[NE];
    __shared__ float sfc[NE];
    int t = blockIdx.x;
    int tid = threadIdx.x;
    for (int i = tid; i < HID / 4; i += 256) {
        ((float4*)xs)[i] = ((const float4*)(x + (size_t)t * HID))[i];
    }
    __syncthreads();
    {
        float4 a = ((const float4*)xs)[tid * 2];
        float4 b = ((const float4*)xs)[tid * 2 + 1];
        short8 o;
        o[0] = (short)f2b(a.x); o[1] = (short)f2b(a.y); o[2] = (short)f2b(a.z); o[3] = (short)f2b(a.w);
        o[4] = (short)f2b(b.x); o[5] = (short)f2b(b.y); o[6] = (short)f2b(b.z); o[7] = (short)f2b(b.w);
        *(short8*)(xb + (size_t)t * HID + tid * 8) = o;
    }
    int e = tid & 31, ch = tid >> 5;
    const float* w = rw + (size_t)e * HID + ch * 256;
    const float* xv = xs + ch * 256;
    float p = 0.f;
    #pragma unroll 8
    for (int k = 0; k < 256; ++k) p += xv[k] * w[k];
    part[tid] = p;
    __syncthreads();
    if (tid < 32) {
        float l = 0.f;
        #pragma unroll
        for (int c = 0; c < 8; ++c) l += part[c * 32 + tid];
        float s = 1.f / (1.f + expf(-l));
        scores[tid] = s;
        sfc[tid] = s + rb[tid];
    }
    __syncthreads();
    if (tid == 0) {
        float gs[NGRP];
        for (int g = 0; g < NGRP; ++g) {
            float v[4];
            for (int i = 0; i < 4; ++i) v[i] = sfc[g * 4 + i];
            int bi = 0;
            for (int i = 1; i < 4; ++i) if (v[i] > v[bi]) bi = i;
            float m1 = v[bi]; v[bi] = -INFINITY;
            int bj = 0;
            for (int i = 1; i < 4; ++i) if (v[i] > v[bj]) bj = i;
            gs[g] = m1 + v[bj];
        }
        bool gsel[NGRP];
        for (int g = 0; g < NGRP; ++g) gsel[g] = false;
        for (int k = 0; k < TOPKG; ++k) {
            int bi = -1; float b = -INFINITY;
            for (int g = 0; g < NGRP; ++g)
                if (!gsel[g] && gs[g] > b) { b = gs[g]; bi = g; }
            gsel[bi] = true;
        }
        float masked[NE];
        for (int i = 0; i < NE; ++i) masked[i] = gsel[i >> 2] ? sfc[i] : 0.0f;
        int sel[TOPK]; float wv[TOPK]; float wsum = 0.f;
        for (int k = 0; k < TOPK; ++k) {
            int bi = -1; float b = -INFINITY;
            for (int i = 0; i < NE; ++i)
                if (masked[i] > b) { b = masked[i]; bi = i; }
            masked[bi] = -INFINITY;
            sel[k] = bi; wv[k] = scores[bi]; wsum += wv[k];
        }
        float inv = RSCALE / (wsum + 1e-20f);
        for (int k = 0; k < TOPK; ++k) {
            tidx[t * TOPK + k] = sel[k];
            tw[t * TOPK + k] = wv[k] * inv;
            atomicAdd(&counts[sel[k]], 1);
        }
    }
}

__global__ void scan_kernel(const int* __restrict__ counts, int* __restrict__ offsets) {
    if (threadIdx.x == 0) {
        int a = 0;
        for (int e2 = 0; e2 < NE; ++e2) { offsets[e2] = a; a += counts[e2]; }
        offsets[NE] = a;                          // = 12288
        for (int j = 1; j <= 4; ++j) offsets[NE + j] = 12288 + j * T_TOK;
    }
}

__global__ void scatter_kernel(const int* __restrict__ tidx, const float* __restrict__ tw,
                               const int* __restrict__ offsets, int* __restrict__ cursors,
                               int* __restrict__ perm, float* __restrict__ pw,
                               int* __restrict__ slot_of) {
    int t = blockIdx.x * blockDim.x + threadIdx.x;
    if (t >= T_TOK) return;
    for (int k = 0; k < TOPK; ++k) {
        int e = tidx[t * TOPK + k];
        int pos = atomicAdd(&cursors[e], 1);
        int slot = offsets[e] + pos;
        perm[slot] = t;
        pw[slot] = tw[t * TOPK + k];
        slot_of[t * TOPK + k] = slot;
    }
    #pragma unroll
    for (int j = 0; j < 4; ++j) {                 // shared pseudo-expert slots
        int slot = 12288 + j * T_TOK + t;
        perm[slot] = t;
        pw[slot] = 1.0f;
    }
}

// ---------------- pure-stream weight cvt: fp32 -> bf16, linear, no transpose ----------------
// chunk ranges (8-elem chunks): w_up 8388608 | w_dn 8388608 | sh_up 1048576 | sh_dn 1048576
__global__ __launch_bounds__(256)
void cvt_weights_kernel(const float* __restrict__ w_up, const float* __restrict__ w_dn,
                        const float* __restrict__ sh_up, const float* __restrict__ sh_dn,
                        unsigned short* __restrict__ wupb, unsigned short* __restrict__ wdnb,
                        unsigned short* __restrict__ shupb, unsigned short* __restrict__ shdnb) {
    size_t c = (size_t)blockIdx.x * 256 + threadIdx.x;
    const float* src; unsigned short* dst; size_t off;
    if (c < 8388608ull)        { src = w_up;  dst = wupb;  off = c; }
    else if (c < 16777216ull)  { src = w_dn;  dst = wdnb;  off = c - 8388608ull; }
    else if (c < 17825792ull)  { src = sh_up; dst = shupb; off = c - 16777216ull; }
    else                       { src = sh_dn; dst = shdnb; off = c - 17825792ull; }
    float4 a = ((const float4*)src)[off * 2];
    float4 b = ((const float4*)src)[off * 2 + 1];
    short8 o;
    o[0] = (short)f2b(a.x); o[1] = (short)f2b(a.y); o[2] = (short)f2b(a.z); o[3] = (short)f2b(a.w);
    o[4] = (short)f2b(b.x); o[5] = (short)f2b(b.y); o[6] = (short)f2b(b.z); o[7] = (short)f2b(b.w);
    *(short8*)(dst + off * 8) = o;
}

// ============================================================================
// GEMM with bf16 [K,N] B staged via global_load_lds into tr_read subtile layout.
// LDS B layout (verified round 8): addr(k,n) = (k>>2)*1024 + (n>>4)*128 + (k&3)*32 + (n&15)*2.
// Wave (wvid) pass p stages k-group kg = wvid+4p (4 k-rows x 128 n = 1KB linear chunk);
// lane i's 16B source: k = kg*4 + ((i>>1)&3), n = (i>>3)*16 + (i&1)*8.
// B-frag: 2x ds_read_b64_tr_b16 at lane base (lane>>4)*2048 + (lane&15)*8 (round-8-verified).
// ============================================================================
template<int MODE>   // 0 = up (C=act bf16 relu2*pw, A gathered via perm), 1 = down (C=slotout bf16)
__global__ __launch_bounds__(256, 2)
void gemm_tr_kernel(const unsigned short* __restrict__ Abuf,
                    const unsigned short* __restrict__ Wmain, const unsigned short* __restrict__ Wsh,
                    unsigned short* __restrict__ Cbuf, const int* __restrict__ offsets,
                    const int* __restrict__ perm, const float* __restrict__ pw) {
    constexpr int K = (MODE == 0) ? HID : DF;
    constexpr int N = (MODE == 0) ? DF : HID;
    __shared__ __align__(16) char lds[32768];
    char* As = lds;
    char* Bs = lds + 16384;

    int tid = threadIdx.x;
    int lane = tid & 63, wvid = tid >> 6, wr = wvid >> 1, wc = wvid & 1;

    int bz = blockIdx.z;
    int off = offsets[bz], end = offsets[bz + 1];
    int row0 = off + blockIdx.y * 128;
    if (row0 >= end) return;
    int n0 = blockIdx.x * 128;

    // B source (bf16, [K,N] natural layout)
    const unsigned short* Bsrc; long ldbb;
    if (MODE == 0) {
        if (bz < NE) { Bsrc = Wmain + (size_t)bz * HID * DF; ldbb = DF; }
        else         { Bsrc = Wsh + (size_t)(bz - NE) * DF;  ldbb = DSZ; }
    } else {
        Bsrc = (bz < NE) ? (Wmain + (size_t)bz * DF * HID)
                         : (Wsh + (size_t)(bz - NE) * DF * HID);
        ldbb = HID;
    }

    // ---- A staging role (global_load_lds, pre-swizzled source chunk) ----
    int lr = lane >> 3;
    int csrc = (((lane & 7) ^ lr) << 4);
    size_t abyte[4];
    int ldsA[4];
    #pragma unroll
    for (int p = 0; p < 4; ++p) {
        int r = p * 32 + wvid * 8 + lr;
        int gr = row0 + r;
        if (gr > end - 1) gr = end - 1;
        int s = (MODE == 0) ? perm[gr] : gr;
        abyte[p] = (size_t)s * (K * 2);
        ldsA[p] = (p * 32 + wvid * 8) * 128;
    }

    // ---- B staging role: per-lane source for subtile layout, linear wave chunks ----
    int bk = (lane >> 1) & 3;
    int bn = (lane >> 3) * 16 + (lane & 1) * 8;
    size_t bbyte[4];
    int ldsB[4];
    #pragma unroll
    for (int p = 0; p < 4; ++p) {
        int kg = wvid + 4 * p;                 // k-group 0..15
        bbyte[p] = ((size_t)(kg * 4 + bk) * ldbb + n0 + bn) * 2;
        ldsB[p] = kg * 1024;
    }

    // ---- B-frag tr_read lane base ----
    unsigned bsb = (unsigned)(uintptr_t)(lv3*)Bs + (unsigned)((lane >> 4) * 2048 + (lane & 15) * 8);

    f32x4 acc[4][4] = {};
    for (int k0 = 0; k0 < K; k0 += 64) {
        size_t kbB = (size_t)k0 * (ldbb * 2);
        __syncthreads();
        #pragma unroll
        for (int p = 0; p < 4; ++p) {
            gload16((const char*)Abuf + abyte[p] + k0 * 2 + csrc, As + ldsA[p]);
            gload16((const char*)Bsrc + kbB + bbyte[p], Bs + ldsB[p]);
        }
        __syncthreads();
        // compute: 2 k-steps of 32
        #pragma unroll
        for (int ks = 0; ks < 2; ++ks) {
            int r16 = lane & 15, kg = lane >> 4;
            short8 af[4];
            #pragma unroll
            for (int m = 0; m < 4; ++m) {
                int r = wr * 64 + m * 16 + r16;
                af[m] = *(const short8*)(As + r * 128 + ((ks * 64 + kg * 16) ^ ((r & 7) << 4)));
            }
            short4v t0[4], t1[4];
            #pragma unroll
            for (int n = 0; n < 4; ++n) {
                unsigned a = bsb + ks * 8192 + (wc * 4 + n) * 128;
                asm volatile("ds_read_b64_tr_b16 %0, %2\n\t"
                             "ds_read_b64_tr_b16 %1, %2 offset:1024"
                             : "=v"(t0[n]), "=v"(t1[n]) : "v"(a));
            }
            asm volatile("s_waitcnt lgkmcnt(0)" ::: "memory");
            __builtin_amdgcn_sched_barrier(0);
            #pragma unroll
            for (int n = 0; n < 4; ++n) {
                short8 bfr;
                bfr[0] = t0[n][0]; bfr[1] = t0[n][1]; bfr[2] = t0[n][2]; bfr[3] = t0[n][3];
                bfr[4] = t1[n][0]; bfr[5] = t1[n][1]; bfr[6] = t1[n][2]; bfr[7] = t1[n][3];
                #pragma unroll
                for (int m = 0; m < 4; ++m)
                    acc[m][n] = __builtin_amdgcn_mfma_f32_16x16x32_bf16(af[m], bfr, acc[m][n], 0, 0, 0);
            }
        }
    }

    // epilogue. D frag: col = lane&15, row = (lane>>4)*4 + j
    int r16 = lane & 15, rg = lane >> 4;
    #pragma unroll
    for (int m = 0; m < 4; ++m) {
        #pragma unroll
        for (int j = 0; j < 4; ++j) {
            int rr = row0 + wr * 64 + m * 16 + rg * 4 + j;
            if (rr < end) {
                if (MODE == 0) {
                    float scale = pw[rr];
                    #pragma unroll
                    for (int n = 0; n < 4; ++n) {
                        int cc = n0 + wc * 64 + n * 16 + r16;
                        float v = acc[m][n][j];
                        v = v > 0.f ? v * v : 0.f;
                        Cbuf[(size_t)rr * N + cc] = f2b(v * scale);
                    }
                } else {
                    #pragma unroll
                    for (int n = 0; n < 4; ++n) {
                        int cc = n0 + wc * 64 + n * 16 + r16;
                        Cbuf[(size_t)rr * N + cc] = f2b(acc[m][n][j]);
                    }
                }
            }
        }
    }
}

// ---------------- combine: out[t] = sum of 6 routed + 4 shared slot rows (bf16 in, f32 out) ----
__global__ void combine_kernel(const unsigned short* __restrict__ slotout,
                               const int* __restrict__ slot_of,
                               float* __restrict__ out) {
    int t = blockIdx.x, tid = threadIdx.x;
    int s[10];
    #pragma unroll
    for (int k = 0; k < TOPK; ++k) s[k] = slot_of[t * TOPK + k];
    #pragma unroll
    for (int j = 0; j < 4; ++j) s[TOPK + j] = 12288 + j * T_TOK + t;
    int c = tid * 8;
    float a[8] = {0.f, 0.f, 0.f, 0.f, 0.f, 0.f, 0.f, 0.f};
    #pragma unroll
    for (int k = 0; k < 10; ++k) {
        short8 v = *(const short8*)(slotout + (size_t)s[k] * HID + c);
        #pragma unroll
        for (int i = 0; i < 8; ++i) a[i] += b2f((unsigned short)v[i]);
    }
    *(float4*)(out + (size_t)t * HID + c) = make_float4(a[0], a[1], a[2], a[3]);
    *(float4*)(out + (size_t)t * HID + c + 4) = make_float4(a[4], a[5], a[6], a[7]);
}

extern "C" void kernel_launch(void* const* d_in, const int* in_sizes, int n_in,
                              void* d_out, int out_size, void* d_ws, size_t ws_size,
                              hipStream_t stream) {
    const float* x     = (const float*)d_in[0];
    const float* rw    = (const float*)d_in[1];
    const float* rb    = (const float*)d_in[2];
    const float* w_up  = (const float*)d_in[3];
    const float* w_dn  = (const float*)d_in[4];
    const float* sh_up = (const float*)d_in[5];
    const float* sh_dn = (const float*)d_in[6];
    float* out = (float*)d_out;
    char* ws = (char*)d_ws;

    int*   counts  = (int*)(ws);
    int*   cursors = (int*)(ws + 128);
    int*   offsets = (int*)(ws + 256);            // 37 ints
    int*   tidx    = (int*)(ws + 1024);           // 12288 int
    float* tw      = (float*)(ws + 50176);        // 12288 f32
    int*   slot_of = (int*)(ws + 99328);          // 12288 int
    int*   perm    = (int*)(ws + 148480);         // 20480 int
    float* pw      = (float*)(ws + 230400);       // 20480 f32
    unsigned short* xb      = (unsigned short*)(ws + 312320);     // [2048][2048] bf16 (8.4MB)
    unsigned short* act     = (unsigned short*)(ws + 8700928);    // [20480][1024] bf16 (41.9MB)
    unsigned short* slotout = (unsigned short*)(ws + 50643968);   // [20480][2048] bf16 (83.9MB)
    unsigned short* wupb    = (unsigned short*)(ws + 134530048);  // 32x[2048][1024] bf16 (134MB)
    unsigned short* wdnb    = (unsigned short*)(ws + 268747776);  // 32x[1024][2048] bf16 (134MB)
    unsigned short* shupb   = (unsigned short*)(ws + 402965504);  // [2048][4096] bf16 (16.8MB)
    unsigned short* shdnb   = (unsigned short*)(ws + 419742720);  // [4096][2048] bf16 (16.8MB)
    // end: 436519936 bytes < 1 GiB

    hipMemsetAsync(ws, 0, 256, stream);  // counts + cursors

    router_kernel<<<T_TOK, 256, 0, stream>>>(x, rw, rb, tidx, tw, counts, xb);
    scan_kernel<<<1, 64, 0, stream>>>(counts, offsets);
    scatter_kernel<<<(T_TOK + 255) / 256, 256, 0, stream>>>(tidx, tw, offsets, cursors,
                                                            perm, pw, slot_of);

    // stream cvt of all four weight tensors (18874368 chunks of 8 elems)
    cvt_weights_kernel<<<73728, 256, 0, stream>>>(w_up, w_dn, sh_up, sh_dn,
                                                  wupb, wdnb, shupb, shdnb);

    // up: A=xb gathered, B=wupb/shupb [K,N] bf16 via tr_read, C=act
    gemm_tr_kernel<0><<<dim3(DF / 128, T_TOK / 128, EXT_E), 256, 0, stream>>>(
        xb, wupb, shupb, act, offsets, perm, pw);

    // down: A=act, B=wdnb/shdnb [K,N] bf16 via tr_read, C=slotout
    gemm_tr_kernel<1><<<dim3(HID / 128, T_TOK / 128, EXT_E), 256, 0, stream>>>(
        act, wdnb, shdnb, slotout, offsets, perm, pw);

    combine_kernel<<<T_TOK, 256, 0, stream>>>(slotout, slot_of, out);
}